// Round 6
// baseline (14961.882 us; speedup 1.0000x reference)
//
#include <hip/hip_runtime.h>
#include <hip/hip_fp16.h>
#include <math.h>

// Persistent RK45 (Dormand-Prince, FSAL) integrator for
//   dy/dt = y * (r + A@y + eps@P[d(t)]),  n=4096, up to 512 adaptive steps.
// R13: atomic-counter barrier + overlapped build with register-consumed k.
//   Ledger: R7 13.35ms (flag->block0->bword hops), R8 13.43 (tagged all-poll,
//   congested), R12 13.98 (flat 256-flag scan from all blocks, +35MB fetch).
//   Three mechanisms at 4.3-4.6us/stage => legs, not flavor, are the cost.
//   (VALU calibration: 9.76% x 13.35ms == ~1000cyc/SIMD/stage x 3072 stages.)
// Changes vs R7:
//  1) Arrival counter: after data-ACK, lane0 does atomicAdd(cnt,1); consumers
//     (tid0) poll ONE hot word for cnt >= 256*gen. Removes the flag store,
//     the 256-flag scan (R12's +35MB), and both block-0 aggregator hops.
//     Monotonic counter -> no reset/parity hazard; es stays deterministic
//     via err_part[] gathered per-block in R7's exact order.
//  2) exchange_build (stages 2-6): pre-build next stage's ys from OLD slots
//     (LDS, stable) while ACK/detect are in flight; after detect, pull the
//     new k by OWN COLUMNS (8 ull, same count as before), fma it from
//     registers (it was always the LAST coefficient -> bitwise-same order),
//     write it to LDS off the critical path; one __syncthreads dropped.
//   Stages 1 & 7 keep classic pull-to-LDS (7's successor needs accept).
// R9/R10: 512-thr workgroups cap VGPR at 128 -> spill; 256-thr only.
// R11: cached pull + per-stage L2 invalidate = +8ms; bypass loads only.
// A stays permanently in registers as fp16 (zero steady-state HBM traffic).

#define N        4096
#define NBLK     256
#define NTHR     256
#define ROWS     16          // rows of A per block (NBLK*ROWS == N)
#define MAXSTEP  512
#define PERTS    8

typedef unsigned long long ull;

static_assert(NBLK * ROWS == N, "row partition");
static_assert(NTHR * 16 == N, "column partition (4 float4 per thread)");

__device__ __forceinline__ float4 ld4(const float* p){ return *reinterpret_cast<const float4*>(p); }
__device__ __forceinline__ void   st4(float* p, float4 v){ *reinterpret_cast<float4*>(p) = v; }

__global__ void __launch_bounds__(NTHR, 1)
mbpert_rk45_kernel(const float* __restrict__ x, const int* __restrict__ tptr,
                   const float* __restrict__ r, const float* __restrict__ A,
                   const float* __restrict__ eps, const float* __restrict__ Pm,
                   float* __restrict__ out, float* __restrict__ W, int Tm)
{
  __shared__ float khist[6][N];        // 96 KB k-history (gfx950: 160KB LDS/WG)
  __shared__ float part_sm[ROWS * 4];  // per-wave matvec partials
  __shared__ float ys_rows[ROWS];      // stage vector at our 16 row indices
  __shared__ float ysb_rows[ROWS];     // base vector at our 16 row indices
  __shared__ float r_sh[ROWS];
  __shared__ float eps_sh[ROWS * PERTS];
  __shared__ float P_sh[32 * PERTS];
  __shared__ float epr_sh[ROWS];
  __shared__ float es_sh;

  const int tid = threadIdx.x;
  const int b   = blockIdx.x;
  const int rowbase = b * ROWS;
  const int lane = tid & 63;
  const int wv   = tid >> 6;

  unsigned* cnt      = reinterpret_cast<unsigned*>(W);       // monotonic arrival counter
  float*    err_part = W + 256;                              // [256] err partials
  ull*      kx0u     = reinterpret_cast<ull*>(W + 1024);     // [N/2] exchange buf A
  ull*      kx1u     = reinterpret_cast<ull*>(W + 1024 + N); // [N/2] exchange buf B

  // ---- persistent LDS constants ----
  if (tid < ROWS)             r_sh[tid]   = r[rowbase + tid];
  if (tid < ROWS * PERTS)     eps_sh[tid] = eps[rowbase * PERTS + tid];
  if (tid < (Tm + 1) * PERTS) P_sh[tid]   = Pm[tid];
  if (tid < ROWS)             ysb_rows[tid] = x[rowbase + tid];

  // ---- A fragment -> registers (fp16), once ----
  // Thread owns cols (q*256+tid)*4..+3 (q=0..3) of rows rowbase..rowbase+15.
  __half2 Af[ROWS][8];
  #pragma unroll
  for (int rr = 0; rr < ROWS; rr++){
    const float* Ar = A + (size_t)(rowbase + rr) * N;
    #pragma unroll
    for (int q = 0; q < 4; q++){
      int c = (q * NTHR + tid) * 4;
      float4 a = ld4(Ar + c);
      Af[rr][2*q]   = __floats2half2_rn(a.x, a.y);
      Af[rr][2*q+1] = __floats2half2_rn(a.z, a.w);
    }
  }

  float4 ysbf[4], ysf[4];              // base / stage vector fragments (fp32)
  #pragma unroll
  for (int q = 0; q < 4; q++) ysbf[q] = ld4(x + (q * NTHR + tid) * 4);
  __syncthreads();

  const float t_end = (float)(*tptr);
  const float Tf    = (float)Tm;
  float t = 0.0f;
  float h = t_end * 0.01f;
  unsigned gen = 0;

  // matvec from registers: acc over our 16 cols, wave-reduce, park in part_sm
  auto mv = [&](){
    float acc[ROWS];
    #pragma unroll
    for (int rr = 0; rr < ROWS; rr++) acc[rr] = 0.0f;
    #pragma unroll
    for (int q = 0; q < 4; q++){
      float4 y = ysf[q];
      #pragma unroll
      for (int rr = 0; rr < ROWS; rr++){
        float2 lo = __half22float2(Af[rr][2*q]);
        float2 hi = __half22float2(Af[rr][2*q+1]);
        acc[rr] = fmaf(lo.x, y.x, fmaf(lo.y, y.y, fmaf(hi.x, y.z, fmaf(hi.y, y.w, acc[rr]))));
      }
    }
    __syncthreads();                   // part_sm free from previous stage; also
                                       // publishes ys_rows/khist writes from the
                                       // preceding exchange_build epilogue
    #pragma unroll
    for (int rr = 0; rr < ROWS; rr++){
      float s = acc[rr];
      #pragma unroll
      for (int off = 32; off; off >>= 1) s += __shfl_xor(s, off, 64);
      if (lane == 0) part_sm[rr * 4 + wv] = s;
    }
    __syncthreads();
  };

  // k for row `tid` (tid<ROWS): y_s * (r + A@y_s + eps@P[d])
  auto kval = [&](float ts) -> float {
    int d = (int)((Tf * ts) / 30.0f);
    d = d < 0 ? 0 : (d > Tm ? Tm : d);
    float dot = part_sm[tid*4] + part_sm[tid*4+1] + part_sm[tid*4+2] + part_sm[tid*4+3];
    float ep = 0.f;
    #pragma unroll
    for (int p = 0; p < PERTS; p++) ep += eps_sh[tid * PERTS + p] * P_sh[d * PERTS + p];
    return ys_rows[tid] * (r_sh[tid] + dot + ep);
  };

  // classic build (stage 2 at loop head): ys = ysb + h * sum(cf[m]*khist[sli[m]])
  auto build = [&](const int* sli, const float* cf, int nk){
    #pragma unroll
    for (int q = 0; q < 4; q++){
      int c = (q * NTHR + tid) * 4;
      float4 v = ysbf[q];
      for (int m = 0; m < nk; m++){
        float cc = h * cf[m];
        float4 kv = ld4(&khist[sli[m]][c]);
        v.x = fmaf(cc, kv.x, v.x); v.y = fmaf(cc, kv.y, v.y);
        v.z = fmaf(cc, kv.z, v.z); v.w = fmaf(cc, kv.w, v.w);
      }
      ysf[q] = v;
      int o = c - rowbase;             // c,rowbase multiples of 4/16: full containment
      if (o >= 0 && o < ROWS) st4(&ys_rows[o], v);
    }
    __syncthreads();
  };

  // publish own 16 k's (+err), ACK, then join the device barrier via counter
  auto publish_and_count = [&](float kv, bool werr, float errv) -> ull* {
    ++gen;
    ull* kx = (gen & 1u) ? kx1u : kx0u;          // double buffer by parity
    if (wv == 0){
      float kvn = __shfl_down(kv, 1, 64);
      if ((lane & 1) == 0 && lane < ROWS){
        union { float2 f; ull u; } cv;
        cv.f = make_float2(kv, kvn);
        __hip_atomic_store(&kx[(rowbase >> 1) + (lane >> 1)], cv.u,
                           __ATOMIC_RELAXED, __HIP_MEMORY_SCOPE_AGENT);
      }
      if (werr && lane == 0)
        __hip_atomic_store(&err_part[b], errv, __ATOMIC_RELAXED, __HIP_MEMORY_SCOPE_AGENT);
      __builtin_amdgcn_sched_barrier(0);
      __builtin_amdgcn_s_waitcnt(0);             // k/err stores at coherence point
      __builtin_amdgcn_sched_barrier(0);
      if (lane == 0)
        __hip_atomic_fetch_add(cnt, 1u, __ATOMIC_RELAXED, __HIP_MEMORY_SCOPE_AGENT);
    }
    return kx;
  };

  // tid0 polls the single hot counter word; barrier releases the block
  auto detect_wait = [&](){
    if (tid == 0){
      const unsigned tgt = gen * (unsigned)NBLK;
      for (;;){
        unsigned c = __hip_atomic_load(cnt, __ATOMIC_RELAXED, __HIP_MEMORY_SCOPE_AGENT);
        if (c >= tgt) break;
        __builtin_amdgcn_s_sleep(1);
      }
    }
    __syncthreads();
  };

  // classic exchange (stages 1 & 7): pull the full k into khist[slot]
  auto exchange = [&](int slot, float kv, bool werr, float errv){
    ull* kx = publish_and_count(kv, werr, errv);
    detect_wait();
    float2* kh2 = reinterpret_cast<float2*>(&khist[slot][0]);
    #pragma unroll
    for (int i = 0; i < 8; i++){                 // coalesced dwordx2 atomic loads
      union { float2 f; ull u; } cv;
      cv.u = __hip_atomic_load(&kx[i * NTHR + tid], __ATOMIC_RELAXED, __HIP_MEMORY_SCOPE_AGENT);
      kh2[i * NTHR + tid] = cv.f;
    }
    if (werr && wv == 0){
      // same order as R7's aggregator -> bitwise-identical es in all blocks
      float es = 0.f;
      #pragma unroll
      for (int j = 0; j < 4; j++)
        es += __hip_atomic_load(&err_part[lane + j * 64],
                                __ATOMIC_RELAXED, __HIP_MEMORY_SCOPE_AGENT);
      #pragma unroll
      for (int off = 32; off; off >>= 1) es += __shfl_xor(es, off, 64);
      if (lane == 0) es_sh = es;
    }
    __syncthreads();                             // khist[slot]/es_sh ready
  };

  // overlapped exchange (stages 1..6 publish): publish k_s, pre-build the
  // NEXT stage's ys from OLD slots during ACK/detect, then consume the new
  // k from registers (it is always the LAST coefficient -> same fma order),
  // and write it to khist[slot_in] off the critical path (mv barrier covers).
  auto exchange_build = [&](int slot_in, float kv,
                            const int* sli_old, const float* cf_old, int nk_old,
                            float cf_new){
    ull* kx = publish_and_count(kv, false, 0.f);
    #pragma unroll
    for (int q = 0; q < 4; q++){                 // partial: old slots (stable LDS)
      int c = (q * NTHR + tid) * 4;
      float4 v = ysbf[q];
      for (int m = 0; m < nk_old; m++){
        float cc = h * cf_old[m];
        float4 kvv = ld4(&khist[sli_old[m]][c]);
        v.x = fmaf(cc, kvv.x, v.x); v.y = fmaf(cc, kvv.y, v.y);
        v.z = fmaf(cc, kvv.z, v.z); v.w = fmaf(cc, kvv.w, v.w);
      }
      ysf[q] = v;
    }
    detect_wait();
    const float cc = h * cf_new;
    #pragma unroll
    for (int q = 0; q < 4; q++){                 // pull OWN columns, fma from regs
      int c = (q * NTHR + tid) * 4;
      union { float2 f; ull u; } c0, c1;
      c0.u = __hip_atomic_load(&kx[(c >> 1)],     __ATOMIC_RELAXED, __HIP_MEMORY_SCOPE_AGENT);
      c1.u = __hip_atomic_load(&kx[(c >> 1) + 1], __ATOMIC_RELAXED, __HIP_MEMORY_SCOPE_AGENT);
      float4 v = ysf[q];
      v.x = fmaf(cc, c0.f.x, v.x); v.y = fmaf(cc, c0.f.y, v.y);
      v.z = fmaf(cc, c1.f.x, v.z); v.w = fmaf(cc, c1.f.y, v.w);
      ysf[q] = v;
      st4(&khist[slot_in][c], make_float4(c0.f.x, c0.f.y, c1.f.x, c1.f.y));
      int o = c - rowbase;
      if (o >= 0 && o < ROWS) st4(&ys_rows[o], v);
    }
    // no trailing __syncthreads: mv()'s first barrier publishes khist/ys_rows
    // before any reader (slot_in is dead to all partial-build lists this step).
  };

  int sl[6] = {0, 1, 2, 3, 4, 5};      // logical k1..k6 -> physical LDS slots
  bool exhausted = true;

  for (int n = 0; n < MAXSTEP; ++n){
    if (n > 0){
      float es = es_sh;                          // set by last stage-7 exchange
      float enorm = sqrtf(es * (1.0f / (float)N));
      bool accept = (enorm <= 1.0f);
      if (accept){
        t += h;
        int tmp = sl[0]; sl[0] = sl[1]; sl[1] = tmp;  // FSAL: k1 <- k7 (in k2's slot)
        #pragma unroll
        for (int q = 0; q < 4; q++) ysbf[q] = ysf[q];
        if (tid < ROWS) ysb_rows[tid] = ys_rows[tid];
      }
      float fac = 0.9f * powf(enorm + 1e-10f, -0.2f);
      fac = fminf(fmaxf(fac, 0.2f), 10.0f);
      h *= fac;
      __syncthreads();
      if (t >= t_end) { exhausted = false; break; }
      h = fminf(h, t_end - t);
      if (!(h > 0.0f)) { exhausted = false; break; }
      // ---- stage-2 build (classic; depends on accept decision) ----
      { const float cf[1] = {0.2f}; const int s_[1] = {sl[0]};
        build(s_, cf, 1); }
    } else {
      if (t >= t_end) { exhausted = false; break; }
      h = fminf(h, t_end - t);
      if (!(h > 0.0f)) { exhausted = false; break; }
      // ---- stage 1 (once ever; FSAL covers later steps) ----
      #pragma unroll
      for (int q = 0; q < 4; q++){
        ysf[q] = ysbf[q];
        int c = (q * NTHR + tid) * 4, o = c - rowbase;
        if (o >= 0 && o < ROWS) st4(&ys_rows[o], ysf[q]);
      }
      __syncthreads();
      mv();
      float kv = (tid < ROWS) ? kval(t) : 0.f;
      exchange_build(sl[0], kv, nullptr, nullptr, 0, 0.2f);   // builds stage-2 ys
    }

    // ---- stage 2: publish k2, pre-build stage-3 ys ----
    mv();
    { float kv = (tid < ROWS) ? kval(t + 0.2f * h) : 0.f;
      const int s_[1] = {sl[0]}; const float cf[1] = {3.f/40.f};
      exchange_build(sl[1], kv, s_, cf, 1, 9.f/40.f); }

    // ---- stage 3: publish k3, pre-build stage-4 ys ----
    mv();
    { float kv = (tid < ROWS) ? kval(t + 0.3f * h) : 0.f;
      const int s_[2] = {sl[0], sl[1]}; const float cf[2] = {44.f/45.f, -56.f/15.f};
      exchange_build(sl[2], kv, s_, cf, 2, 32.f/9.f); }

    // ---- stage 4: publish k4, pre-build stage-5 ys ----
    mv();
    { float kv = (tid < ROWS) ? kval(t + 0.8f * h) : 0.f;
      const int s_[3] = {sl[0], sl[1], sl[2]};
      const float cf[3] = {19372.f/6561.f, -25360.f/2187.f, 64448.f/6561.f};
      exchange_build(sl[3], kv, s_, cf, 3, -212.f/729.f); }

    // ---- stage 5: publish k5, pre-build stage-6 ys ----
    mv();
    { float kv = (tid < ROWS) ? kval(t + (8.f/9.f) * h) : 0.f;
      const int s_[4] = {sl[0], sl[1], sl[2], sl[3]};
      const float cf[4] = {9017.f/3168.f, -355.f/33.f, 46732.f/5247.f, 49.f/176.f};
      exchange_build(sl[4], kv, s_, cf, 4, -5103.f/18656.f); }

    // ---- stage 6: publish k6, pre-build stage-7 ys (= y5 candidate) ----
    mv();
    { float kv = (tid < ROWS) ? kval(t + h) : 0.f;
      const int s_[4] = {sl[0], sl[2], sl[3], sl[4]};
      const float cf[4] = {35.f/384.f, 500.f/1113.f, 125.f/192.f, -2187.f/6784.f};
      exchange_build(sl[5], kv, s_, cf, 4, 11.f/84.f); }

    // ---- stage 7: err partial; classic exchange (k7 -> sl[1], k2 dead) ----
    mv();
    { float k7v = 0.f, errv = 0.f;
      if (tid < ROWS){
        k7v = kval(t + h);
        int gi = rowbase + tid;
        float e = (71.f/57600.f)  * khist[sl[0]][gi] - (71.f/16695.f)    * khist[sl[2]][gi]
                + (71.f/1920.f)   * khist[sl[3]][gi] - (17253.f/339200.f)* khist[sl[4]][gi]
                + (22.f/525.f)    * khist[sl[5]][gi] - (1.f/40.f)        * k7v;
        e *= h;
        float sc = 1e-6f + 1e-3f * fmaxf(fabsf(ysb_rows[tid]), fabsf(ys_rows[tid]));
        float q = e / sc;
        epr_sh[tid] = q * q;
      }
      __syncthreads();
      if (tid == 0){
        float s = 0.f;
        #pragma unroll
        for (int i = 0; i < ROWS; i++) s += epr_sh[i];
        errv = s;
      }
      exchange(sl[1], k7v, true, errv); }        // barrier + err + k7 fetch
  }

  if (exhausted){
    // apply the final (iteration 511) accept decision, as the reference does
    float es = es_sh;
    bool accept = sqrtf(es * (1.0f / (float)N)) <= 1.0f;
    if (tid < ROWS) out[rowbase + tid] = accept ? ys_rows[tid] : ysb_rows[tid];
  } else {
    if (tid < ROWS) out[rowbase + tid] = ysb_rows[tid];
  }
}

extern "C" void kernel_launch(void* const* d_in, const int* in_sizes, int n_in,
                              void* d_out, int out_size, void* d_ws, size_t ws_size,
                              hipStream_t stream)
{
  const float* x   = (const float*)d_in[0];
  const int*   tp  = (const int*)  d_in[1];
  const float* r   = (const float*)d_in[2];
  const float* A   = (const float*)d_in[3];
  const float* eps = (const float*)d_in[4];
  const float* Pm  = (const float*)d_in[5];
  float* out = (float*)d_out;
  float* W   = (float*)d_ws;
  int Tm = in_sizes[5] / PERTS - 1;   // P rows - 1  (== 30)

  // zero counter / err partials (ws re-poisoned per call)
  hipMemsetAsync(d_ws, 0, 4096, stream);
  mbpert_rk45_kernel<<<dim3(NBLK), dim3(NTHR), 0, stream>>>(
      x, tp, r, A, eps, Pm, out, W, Tm);
}

// Round 7
// 12367.445 us; speedup vs baseline: 1.2098x; 1.2098x over previous
//
#include <hip/hip_runtime.h>
#include <hip/hip_fp16.h>
#include <math.h>

// Persistent RK45 (Dormand-Prince, FSAL) integrator for
//   dy/dt = y * (r + A@y + eps@P[d(t)]),  n=4096, up to 512 adaptive steps.
// R14 = R7's barrier (cheapest measured) + R13's overlap (bitwise-safe).
//   Barrier ledger (us/stage): R7 flag+block0-aggregator 4.34 | R8 tagged
//   4.37 | R12 flat-scan 4.55 | R13 atomic-counter 4.87 (256 RMWs serialize
//   ~0.85us on one line). R13's overlap (pre-build next ys from OLD LDS
//   slots during detect; consume new k from registers as the LAST fma
//   coefficient -> bitwise-same order) is worth ~0.3us but was buried under
//   the counter cost. R14 composes R7 barrier + R13 overlap verbatim.
// R11: L2-cached pull + per-stage invalidate fence = +8ms. Bypass only.
// R9/R10: 512-thr workgroups cap VGPR at 128 -> Af spills; 256-thr only.
// A stays permanently in registers as fp16 (zero steady-state HBM traffic).

#define N        4096
#define NBLK     256
#define NTHR     256
#define ROWS     16          // rows of A per block (NBLK*ROWS == N)
#define MAXSTEP  512
#define PERTS    8

typedef unsigned long long ull;

static_assert(NBLK * ROWS == N, "row partition");
static_assert(NTHR * 16 == N, "column partition (4 float4 per thread)");

__device__ __forceinline__ float4 ld4(const float* p){ return *reinterpret_cast<const float4*>(p); }
__device__ __forceinline__ void   st4(float* p, float4 v){ *reinterpret_cast<float4*>(p) = v; }

__global__ void __launch_bounds__(NTHR, 1)
mbpert_rk45_kernel(const float* __restrict__ x, const int* __restrict__ tptr,
                   const float* __restrict__ r, const float* __restrict__ A,
                   const float* __restrict__ eps, const float* __restrict__ Pm,
                   float* __restrict__ out, float* __restrict__ W, int Tm)
{
  __shared__ float khist[6][N];        // 96 KB k-history (gfx950: 160KB LDS/WG)
  __shared__ float part_sm[ROWS * 4];  // per-wave matvec partials
  __shared__ float ys_rows[ROWS];      // stage vector at our 16 row indices
  __shared__ float ysb_rows[ROWS];     // base vector at our 16 row indices
  __shared__ float r_sh[ROWS];
  __shared__ float eps_sh[ROWS * PERTS];
  __shared__ float P_sh[32 * PERTS];
  __shared__ float epr_sh[ROWS];
  __shared__ float es_sh;

  const int tid = threadIdx.x;
  const int b   = blockIdx.x;
  const int rowbase = b * ROWS;
  const int lane = tid & 63;
  const int wv   = tid >> 6;

  unsigned* flags    = reinterpret_cast<unsigned*>(W);       // [256] per-block stage flags
  float*    err_part = W + 256;                              // [256] err partials
  ull*      bword    = reinterpret_cast<ull*>(W + 512);      // packed (gen<<32 | err bits)
  ull*      kx0u     = reinterpret_cast<ull*>(W + 1024);     // [N/2] exchange buf A
  ull*      kx1u     = reinterpret_cast<ull*>(W + 1024 + N); // [N/2] exchange buf B

  // ---- persistent LDS constants ----
  if (tid < ROWS)             r_sh[tid]   = r[rowbase + tid];
  if (tid < ROWS * PERTS)     eps_sh[tid] = eps[rowbase * PERTS + tid];
  if (tid < (Tm + 1) * PERTS) P_sh[tid]   = Pm[tid];
  if (tid < ROWS)             ysb_rows[tid] = x[rowbase + tid];

  // ---- A fragment -> registers (fp16), once ----
  // Thread owns cols (q*256+tid)*4..+3 (q=0..3) of rows rowbase..rowbase+15.
  __half2 Af[ROWS][8];
  #pragma unroll
  for (int rr = 0; rr < ROWS; rr++){
    const float* Ar = A + (size_t)(rowbase + rr) * N;
    #pragma unroll
    for (int q = 0; q < 4; q++){
      int c = (q * NTHR + tid) * 4;
      float4 a = ld4(Ar + c);
      Af[rr][2*q]   = __floats2half2_rn(a.x, a.y);
      Af[rr][2*q+1] = __floats2half2_rn(a.z, a.w);
    }
  }

  float4 ysbf[4], ysf[4];              // base / stage vector fragments (fp32)
  #pragma unroll
  for (int q = 0; q < 4; q++) ysbf[q] = ld4(x + (q * NTHR + tid) * 4);
  __syncthreads();

  const float t_end = (float)(*tptr);
  const float Tf    = (float)Tm;
  float t = 0.0f;
  float h = t_end * 0.01f;
  unsigned gen = 0;

  // matvec from registers: acc over our 16 cols, wave-reduce, park in part_sm
  auto mv = [&](){
    float acc[ROWS];
    #pragma unroll
    for (int rr = 0; rr < ROWS; rr++) acc[rr] = 0.0f;
    #pragma unroll
    for (int q = 0; q < 4; q++){
      float4 y = ysf[q];
      #pragma unroll
      for (int rr = 0; rr < ROWS; rr++){
        float2 lo = __half22float2(Af[rr][2*q]);
        float2 hi = __half22float2(Af[rr][2*q+1]);
        acc[rr] = fmaf(lo.x, y.x, fmaf(lo.y, y.y, fmaf(hi.x, y.z, fmaf(hi.y, y.w, acc[rr]))));
      }
    }
    __syncthreads();                   // part_sm free; also publishes the
                                       // preceding exchange_build epilogue's
                                       // khist/ys_rows LDS writes
    #pragma unroll
    for (int rr = 0; rr < ROWS; rr++){
      float s = acc[rr];
      #pragma unroll
      for (int off = 32; off; off >>= 1) s += __shfl_xor(s, off, 64);
      if (lane == 0) part_sm[rr * 4 + wv] = s;
    }
    __syncthreads();
  };

  // k for row `tid` (tid<ROWS): y_s * (r + A@y_s + eps@P[d])
  auto kval = [&](float ts) -> float {
    int d = (int)((Tf * ts) / 30.0f);
    d = d < 0 ? 0 : (d > Tm ? Tm : d);
    float dot = part_sm[tid*4] + part_sm[tid*4+1] + part_sm[tid*4+2] + part_sm[tid*4+3];
    float ep = 0.f;
    #pragma unroll
    for (int p = 0; p < PERTS; p++) ep += eps_sh[tid * PERTS + p] * P_sh[d * PERTS + p];
    return ys_rows[tid] * (r_sh[tid] + dot + ep);
  };

  // classic build (stage-2 at loop head; depends on accept decision)
  auto build = [&](const int* sli, const float* cf, int nk){
    #pragma unroll
    for (int q = 0; q < 4; q++){
      int c = (q * NTHR + tid) * 4;
      float4 v = ysbf[q];
      for (int m = 0; m < nk; m++){
        float cc = h * cf[m];
        float4 kv = ld4(&khist[sli[m]][c]);
        v.x = fmaf(cc, kv.x, v.x); v.y = fmaf(cc, kv.y, v.y);
        v.z = fmaf(cc, kv.z, v.z); v.w = fmaf(cc, kv.w, v.w);
      }
      ysf[q] = v;
      int o = c - rowbase;             // c,rowbase multiples of 4/16: full containment
      if (o >= 0 && o < ROWS) st4(&ys_rows[o], v);
    }
    __syncthreads();
  };

  // R7 publish: wave0 stores 16 k's (+err), block barrier, tid0 ACK + flag
  auto publish_flag = [&](float kv, bool werr, float errv) -> ull* {
    ++gen;
    ull* kx = (gen & 1u) ? kx1u : kx0u;          // double buffer by parity
    if (wv == 0){
      float kvn = __shfl_down(kv, 1, 64);
      if ((lane & 1) == 0 && lane < ROWS){
        union { float2 f; ull u; } cv;
        cv.f = make_float2(kv, kvn);
        __hip_atomic_store(&kx[(rowbase >> 1) + (lane >> 1)], cv.u,
                           __ATOMIC_RELAXED, __HIP_MEMORY_SCOPE_AGENT);
      }
      if (werr && lane == 0)
        __hip_atomic_store(&err_part[b], errv, __ATOMIC_RELAXED, __HIP_MEMORY_SCOPE_AGENT);
    }
    __syncthreads();                             // all stage work done
    if (tid == 0){
      __builtin_amdgcn_sched_barrier(0);
      __builtin_amdgcn_s_waitcnt(0);             // kx/err stores at coherence point
      __builtin_amdgcn_sched_barrier(0);
      __hip_atomic_store(&flags[b], gen, __ATOMIC_RELAXED, __HIP_MEMORY_SCOPE_AGENT);
    }
    return kx;
  };

  // R7 detect: block0 scans all flags, broadcasts one packed (gen,err) word
  auto detect = [&](bool werr){
    if (b == 0){
      if (wv == 0){
        for (;;){
          bool ok = true;
          #pragma unroll
          for (int j = 0; j < 4; j++){
            unsigned f = __hip_atomic_load(&flags[j * 64 + lane],
                                           __ATOMIC_RELAXED, __HIP_MEMORY_SCOPE_AGENT);
            ok = ok && (f >= gen);
          }
          if (__all(ok)) break;
          __builtin_amdgcn_s_sleep(2);
        }
        float es = 0.f;
        if (werr){                               // R7 order -> bitwise identical
          #pragma unroll
          for (int j = 0; j < 4; j++)
            es += __hip_atomic_load(&err_part[lane + j * 64],
                                    __ATOMIC_RELAXED, __HIP_MEMORY_SCOPE_AGENT);
          #pragma unroll
          for (int off = 32; off; off >>= 1) es += __shfl_xor(es, off, 64);
        }
        if (lane == 0){
          if (werr) es_sh = es;
          ull pk = ((ull)gen << 32) | (ull)__float_as_uint(es);
          __builtin_amdgcn_sched_barrier(0);
          __builtin_amdgcn_s_waitcnt(0);
          __builtin_amdgcn_sched_barrier(0);
          __hip_atomic_store(bword, pk, __ATOMIC_RELAXED, __HIP_MEMORY_SCOPE_AGENT);
        }
      }
      __syncthreads();
    } else {
      if (tid == 0){
        for (;;){
          ull w = __hip_atomic_load(bword, __ATOMIC_RELAXED, __HIP_MEMORY_SCOPE_AGENT);
          if ((unsigned)(w >> 32) >= gen){
            if (werr) es_sh = __uint_as_float((unsigned)(w & 0xffffffffu));
            break;
          }
          __builtin_amdgcn_s_sleep(2);
        }
      }
      __syncthreads();
    }
  };

  // classic exchange (stage 7): publish, detect(+err), pull full k into LDS
  auto exchange = [&](int slot, float kv, bool werr, float errv){
    ull* kx = publish_flag(kv, werr, errv);
    detect(werr);
    float2* kh2 = reinterpret_cast<float2*>(&khist[slot][0]);
    #pragma unroll
    for (int i = 0; i < 8; i++){                 // coalesced dwordx2 atomic loads
      union { float2 f; ull u; } cv;
      cv.u = __hip_atomic_load(&kx[i * NTHR + tid], __ATOMIC_RELAXED, __HIP_MEMORY_SCOPE_AGENT);
      kh2[i * NTHR + tid] = cv.f;
    }
    __syncthreads();                             // khist[slot]/es_sh ready
  };

  // overlapped exchange (stages 1..6): publish k_s, pre-build NEXT stage's ys
  // from OLD slots during flag propagation/detect, then consume the new k
  // from registers (always the LAST coefficient -> bitwise-same fma order),
  // park it in khist[slot_in] off the critical path (mv barrier publishes).
  auto exchange_build = [&](int slot_in, float kv,
                            const int* sli_old, const float* cf_old, int nk_old,
                            float cf_new){
    ull* kx = publish_flag(kv, false, 0.f);
    #pragma unroll
    for (int q = 0; q < 4; q++){                 // partial: old slots (stable LDS)
      int c = (q * NTHR + tid) * 4;
      float4 v = ysbf[q];
      for (int m = 0; m < nk_old; m++){
        float cc = h * cf_old[m];
        float4 kvv = ld4(&khist[sli_old[m]][c]);
        v.x = fmaf(cc, kvv.x, v.x); v.y = fmaf(cc, kvv.y, v.y);
        v.z = fmaf(cc, kvv.z, v.z); v.w = fmaf(cc, kvv.w, v.w);
      }
      ysf[q] = v;
    }
    detect(false);
    const float cc = h * cf_new;
    #pragma unroll
    for (int q = 0; q < 4; q++){                 // pull OWN columns, fma from regs
      int c = (q * NTHR + tid) * 4;
      union { float2 f; ull u; } c0, c1;
      c0.u = __hip_atomic_load(&kx[(c >> 1)],     __ATOMIC_RELAXED, __HIP_MEMORY_SCOPE_AGENT);
      c1.u = __hip_atomic_load(&kx[(c >> 1) + 1], __ATOMIC_RELAXED, __HIP_MEMORY_SCOPE_AGENT);
      float4 v = ysf[q];
      v.x = fmaf(cc, c0.f.x, v.x); v.y = fmaf(cc, c0.f.y, v.y);
      v.z = fmaf(cc, c1.f.x, v.z); v.w = fmaf(cc, c1.f.y, v.w);
      ysf[q] = v;
      st4(&khist[slot_in][c], make_float4(c0.f.x, c0.f.y, c1.f.x, c1.f.y));
      int o = c - rowbase;
      if (o >= 0 && o < ROWS) st4(&ys_rows[o], v);
    }
    // no trailing __syncthreads: mv()'s first barrier publishes khist/ys_rows
    // (slot_in is dead to every partial-build list in this step).
  };

  int sl[6] = {0, 1, 2, 3, 4, 5};      // logical k1..k6 -> physical LDS slots
  bool exhausted = true;

  for (int n = 0; n < MAXSTEP; ++n){
    if (n > 0){
      float es = es_sh;                          // set by last stage-7 exchange
      float enorm = sqrtf(es * (1.0f / (float)N));
      bool accept = (enorm <= 1.0f);
      if (accept){
        t += h;
        int tmp = sl[0]; sl[0] = sl[1]; sl[1] = tmp;  // FSAL: k1 <- k7 (in k2's slot)
        #pragma unroll
        for (int q = 0; q < 4; q++) ysbf[q] = ysf[q];
        if (tid < ROWS) ysb_rows[tid] = ys_rows[tid];
      }
      float fac = 0.9f * powf(enorm + 1e-10f, -0.2f);
      fac = fminf(fmaxf(fac, 0.2f), 10.0f);
      h *= fac;
      __syncthreads();
      if (t >= t_end) { exhausted = false; break; }
      h = fminf(h, t_end - t);
      if (!(h > 0.0f)) { exhausted = false; break; }
      // ---- stage-2 build (classic; depends on accept decision) ----
      { const float cf[1] = {0.2f}; const int s_[1] = {sl[0]};
        build(s_, cf, 1); }
    } else {
      if (t >= t_end) { exhausted = false; break; }
      h = fminf(h, t_end - t);
      if (!(h > 0.0f)) { exhausted = false; break; }
      // ---- stage 1 (once ever; FSAL covers later steps) ----
      #pragma unroll
      for (int q = 0; q < 4; q++){
        ysf[q] = ysbf[q];
        int c = (q * NTHR + tid) * 4, o = c - rowbase;
        if (o >= 0 && o < ROWS) st4(&ys_rows[o], ysf[q]);
      }
      __syncthreads();
      mv();
      float kv = (tid < ROWS) ? kval(t) : 0.f;
      exchange_build(sl[0], kv, nullptr, nullptr, 0, 0.2f);   // builds stage-2 ys
    }

    // ---- stage 2: publish k2, pre-build stage-3 ys ----
    mv();
    { float kv = (tid < ROWS) ? kval(t + 0.2f * h) : 0.f;
      const int s_[1] = {sl[0]}; const float cf[1] = {3.f/40.f};
      exchange_build(sl[1], kv, s_, cf, 1, 9.f/40.f); }

    // ---- stage 3: publish k3, pre-build stage-4 ys ----
    mv();
    { float kv = (tid < ROWS) ? kval(t + 0.3f * h) : 0.f;
      const int s_[2] = {sl[0], sl[1]}; const float cf[2] = {44.f/45.f, -56.f/15.f};
      exchange_build(sl[2], kv, s_, cf, 2, 32.f/9.f); }

    // ---- stage 4: publish k4, pre-build stage-5 ys ----
    mv();
    { float kv = (tid < ROWS) ? kval(t + 0.8f * h) : 0.f;
      const int s_[3] = {sl[0], sl[1], sl[2]};
      const float cf[3] = {19372.f/6561.f, -25360.f/2187.f, 64448.f/6561.f};
      exchange_build(sl[3], kv, s_, cf, 3, -212.f/729.f); }

    // ---- stage 5: publish k5, pre-build stage-6 ys ----
    mv();
    { float kv = (tid < ROWS) ? kval(t + (8.f/9.f) * h) : 0.f;
      const int s_[4] = {sl[0], sl[1], sl[2], sl[3]};
      const float cf[4] = {9017.f/3168.f, -355.f/33.f, 46732.f/5247.f, 49.f/176.f};
      exchange_build(sl[4], kv, s_, cf, 4, -5103.f/18656.f); }

    // ---- stage 6: publish k6, pre-build stage-7 ys (= y5 candidate) ----
    mv();
    { float kv = (tid < ROWS) ? kval(t + h) : 0.f;
      const int s_[4] = {sl[0], sl[2], sl[3], sl[4]};
      const float cf[4] = {35.f/384.f, 500.f/1113.f, 125.f/192.f, -2187.f/6784.f};
      exchange_build(sl[5], kv, s_, cf, 4, 11.f/84.f); }

    // ---- stage 7: err partial; classic exchange (k7 -> sl[1], k2 dead) ----
    mv();
    { float k7v = 0.f, errv = 0.f;
      if (tid < ROWS){
        k7v = kval(t + h);
        int gi = rowbase + tid;
        float e = (71.f/57600.f)  * khist[sl[0]][gi] - (71.f/16695.f)    * khist[sl[2]][gi]
                + (71.f/1920.f)   * khist[sl[3]][gi] - (17253.f/339200.f)* khist[sl[4]][gi]
                + (22.f/525.f)    * khist[sl[5]][gi] - (1.f/40.f)        * k7v;
        e *= h;
        float sc = 1e-6f + 1e-3f * fmaxf(fabsf(ysb_rows[tid]), fabsf(ys_rows[tid]));
        float q = e / sc;
        epr_sh[tid] = q * q;
      }
      __syncthreads();
      if (tid == 0){
        float s = 0.f;
        #pragma unroll
        for (int i = 0; i < ROWS; i++) s += epr_sh[i];
        errv = s;
      }
      exchange(sl[1], k7v, true, errv); }        // barrier + err broadcast + k7 fetch
  }

  if (exhausted){
    // apply the final (iteration 511) accept decision, as the reference does
    float es = es_sh;
    bool accept = sqrtf(es * (1.0f / (float)N)) <= 1.0f;
    if (tid < ROWS) out[rowbase + tid] = accept ? ys_rows[tid] : ysb_rows[tid];
  } else {
    if (tid < ROWS) out[rowbase + tid] = ysb_rows[tid];
  }
}

extern "C" void kernel_launch(void* const* d_in, const int* in_sizes, int n_in,
                              void* d_out, int out_size, void* d_ws, size_t ws_size,
                              hipStream_t stream)
{
  const float* x   = (const float*)d_in[0];
  const int*   tp  = (const int*)  d_in[1];
  const float* r   = (const float*)d_in[2];
  const float* A   = (const float*)d_in[3];
  const float* eps = (const float*)d_in[4];
  const float* Pm  = (const float*)d_in[5];
  float* out = (float*)d_out;
  float* W   = (float*)d_ws;
  int Tm = in_sizes[5] / PERTS - 1;   // P rows - 1  (== 30)

  // zero flags / err partials / broadcast word (ws re-poisoned per call)
  hipMemsetAsync(d_ws, 0, 4096, stream);
  mbpert_rk45_kernel<<<dim3(NBLK), dim3(NTHR), 0, stream>>>(
      x, tp, r, A, eps, Pm, out, W, Tm);
}